// Round 2
// baseline (13429.927 us; speedup 1.0000x reference)
//
#include <hip/hip_runtime.h>
#include <hip/hip_bf16.h>
#include <math.h>

#define BB 4
#define TT 4096
#define DIMW 1024
#define HID 1536
#define HID2 3072
#define KC 4
#define SSEG 16
#define LSEG 256
#define DD 384
#define NCH 64          // scan chunks per batch
#define CHL 64          // tokens per chunk (NCH*CHL == TT)
#define TH  ((size_t)TT*(size_t)HID)   // elements in one T x HID slot

// =====================================================================
// Generic GEMM: C[m,n] = sum_k A[m,k] * W[n,k]   (W always fp32 weights)
// fp64 accumulation. Tile 64x64, BK=16, 256 threads, 4x4 doubles/thread.
// MODE 0: plain store to C0 (row stride Nout)
// MODE 1: split columns [0,HID)->C0, [HID,2HID)->C1 (both row stride HID)
// MODE 2: C0[m*Nout+n] = silu(acc) * X[m*Nout+n]
// =====================================================================
template<typename AT, typename CT, int MODE>
__global__ __launch_bounds__(256) void gemm_tn(const AT* __restrict__ A,
                                               const float* __restrict__ W,
                                               CT* __restrict__ C0,
                                               CT* __restrict__ C1,
                                               const double* __restrict__ X,
                                               int M, int Nout, int Kd)
{
    __shared__ double As[16][64];
    __shared__ double Ws[16][64];
    const int tid = threadIdx.x;
    const int m0 = blockIdx.x * 64;
    const int n0 = blockIdx.y * 64;
    const int tx = tid & 15, ty = tid >> 4;
    double acc[4][4];
#pragma unroll
    for (int i = 0; i < 4; i++)
#pragma unroll
        for (int j = 0; j < 4; j++) acc[i][j] = 0.0;

    const int lrow = tid >> 2;      // 0..63
    const int kq   = (tid & 3) * 4; // 0,4,8,12

    for (int k0 = 0; k0 < Kd; k0 += 16) {
        const long arow = (long)(m0 + lrow);
#pragma unroll
        for (int u = 0; u < 4; u++) {
            double v = 0.0;
            if (arow < M) v = (double)A[arow * (long)Kd + (k0 + kq + u)];
            As[kq + u][lrow] = v;
        }
        const long wrow = (long)(n0 + lrow);
#pragma unroll
        for (int u = 0; u < 4; u++) {
            double v = 0.0;
            if (wrow < Nout) v = (double)W[wrow * (long)Kd + (k0 + kq + u)];
            Ws[kq + u][lrow] = v;
        }
        __syncthreads();
#pragma unroll
        for (int k = 0; k < 16; k++) {
            double av[4], bv[4];
#pragma unroll
            for (int i = 0; i < 4; i++) av[i] = As[k][ty * 4 + i];
#pragma unroll
            for (int j = 0; j < 4; j++) bv[j] = Ws[k][tx * 4 + j];
#pragma unroll
            for (int i = 0; i < 4; i++)
#pragma unroll
                for (int j = 0; j < 4; j++) acc[i][j] += av[i] * bv[j];
        }
        __syncthreads();
    }
#pragma unroll
    for (int i = 0; i < 4; i++) {
        const int m = m0 + ty * 4 + i;
        if (m >= M) continue;
#pragma unroll
        for (int j = 0; j < 4; j++) {
            const int n = n0 + tx * 4 + j;
            if (n >= Nout) continue;
            if constexpr (MODE == 1) {
                if (n < HID) C0[(long)m * HID + n] = (CT)acc[i][j];
                else         C1[(long)m * HID + (n - HID)] = (CT)acc[i][j];
            } else if constexpr (MODE == 2) {
                double g = acc[i][j];
                double v = (g / (1.0 + exp(-g))) * X[(long)m * Nout + n];
                C0[(long)m * Nout + n] = (CT)v;
            } else {
                C0[(long)m * Nout + n] = (CT)acc[i][j];
            }
        }
    }
}

// softplus(forget_base) per channel (once)
__global__ __launch_bounds__(256) void spb_kernel(const float* __restrict__ fb,
                                                  double* __restrict__ spb)
{
    int h = blockIdx.x * 256 + threadIdx.x;
    if (h < HID) {
        double xv = (double)fb[h];
        spb[h] = log1p(exp(xv));
    }
}

// causal depthwise conv (one batch): out[t,h] = cb[h] + sum_j cw[h,j]*x[t-3+j,h]
__global__ __launch_bounds__(256) void conv_kernel(const double* __restrict__ xin,
                                                   const float* __restrict__ cw,
                                                   const float* __restrict__ cb,
                                                   double* __restrict__ outp)
{
    size_t i = (size_t)blockIdx.x * 256 + threadIdx.x;
    if (i >= TH) return;
    int h = (int)(i % HID);
    int t = (int)(i / HID);
    double acc = (double)cb[h];
#pragma unroll
    for (int j = 0; j < KC; j++) {
        int tt = t - (KC - 1) + j;
        if (tt >= 0) acc += (double)cw[h * KC + j] * xin[(size_t)tt * HID + h];
    }
    outp[i] = acc;
}

// raw forget(fg)/inp(ip) (+bias) -> alpha, xh2 : fully in-place, reads xh1
__global__ __launch_bounds__(256) void alpha_xh2_kernel(double* __restrict__ fg,
                                                        double* __restrict__ ip,
                                                        const double* __restrict__ xh1,
                                                        const double* __restrict__ spb,
                                                        const float* __restrict__ gb)
{
    size_t i = (size_t)blockIdx.x * 256 + threadIdx.x;
    if (i >= TH) return;
    int h = (int)(i % HID);
    double f  = fg[i] + (double)gb[h];
    double g2 = ip[i] + (double)gb[HID + h];
    double sigf = 1.0 / (1.0 + exp(-f));
    double alpha = exp(-8.0 * spb[h] * sigf);
    double s2 = sqrt(1.0 - alpha * alpha + 1e-6);
    double sigi = 1.0 / (1.0 + exp(-g2));
    double x1 = xh1[i];
    fg[i] = alpha;
    ip[i] = s2 * sigi * x1;
}

// scan pass1 (one batch): per (h,chunk) local prefix value + alpha product
__global__ __launch_bounds__(256) void scan1_kernel(const double* __restrict__ alpha,
                                                    const double* __restrict__ xh2,
                                                    double* __restrict__ cA,
                                                    double* __restrict__ cB)
{
    int idx = blockIdx.x * 256 + threadIdx.x;  // c*HID + h
    if (idx >= NCH * HID) return;
    int h = idx % HID;
    int c = idx / HID;
    size_t base = (size_t)c * CHL * HID + h;
    double aP = 1.0, bV = 0.0;
    for (int i = 0; i < CHL; i++) {
        double a  = alpha[base + (size_t)i * HID];
        double xv = xh2 [base + (size_t)i * HID];
        bV = a * bV + xv;
        aP *= a;
    }
    size_t o = (size_t)c * HID + h;
    cA[o] = aP;
    cB[o] = bV;
}

// scan pass2 (one batch): chunk carry-in per h
__global__ __launch_bounds__(256) void scan2_kernel(const double* __restrict__ cA,
                                                    const double* __restrict__ cB,
                                                    double* __restrict__ cH0)
{
    int h = blockIdx.x * 256 + threadIdx.x;
    if (h >= HID) return;
    double carry = 0.0;
    for (int c = 0; c < NCH; c++) {
        size_t o = (size_t)c * HID + h;
        cH0[o] = carry;
        carry = cA[o] * carry + cB[o];
    }
}

// scan pass3 (one batch): replay with carry-in, write h
__global__ __launch_bounds__(256) void scan3_kernel(const double* __restrict__ alpha,
                                                    const double* __restrict__ xh2,
                                                    const double* __restrict__ cH0,
                                                    double* __restrict__ hout)
{
    int idx = blockIdx.x * 256 + threadIdx.x;
    if (idx >= NCH * HID) return;
    int h = idx % HID;
    int c = idx / HID;
    size_t base = (size_t)c * CHL * HID + h;
    double hv = cH0[(size_t)c * HID + h];
    for (int i = 0; i < CHL; i++) {
        double a  = alpha[base + (size_t)i * HID];
        double xv = xh2 [base + (size_t)i * HID];
        hv = a * hv + xv;
        hout[base + (size_t)i * HID] = hv;
    }
}

// xr = gelu_exact(xh3)*h, in-place over xh3
__global__ __launch_bounds__(256) void gelu_mul_kernel(double* __restrict__ xh3,
                                                       const double* __restrict__ hbuf)
{
    size_t i = (size_t)blockIdx.x * 256 + threadIdx.x;
    if (i >= TH) return;
    double x3 = xh3[i];
    double ge = 0.5 * x3 * (1.0 + erf(x3 * 0.70710678118654752440));
    xh3[i] = ge * hbuf[i];
}

// attention 1 (one batch): per segment s, softmax over l=256, mem[s,:] = sum attn*v
__global__ __launch_bounds__(256) void attn1_kernel(const double* __restrict__ kmat,
                                                    const double* __restrict__ vmat,
                                                    const double* __restrict__ qbuf,
                                                    double* __restrict__ mem)
{
    const int s = blockIdx.x;
    const int l = threadIdx.x;
    const size_t row = (size_t)s * LSEG + l;
    const double* kr = kmat + row * DD;
    const double* qs = qbuf + (size_t)s * DD;
    double acc = 0.0;
    for (int d = 0; d < DD; d++) acc += qs[d] * kr[d];
    double qk = acc / sqrt((double)DD);
    __shared__ double r1[256];
    __shared__ double sw[256];
    r1[l] = qk; __syncthreads();
    for (int off = 128; off > 0; off >>= 1) {
        if (l < off) r1[l] = fmax(r1[l], r1[l + off]);
        __syncthreads();
    }
    double m = r1[0]; __syncthreads();
    double e = exp(qk - m);
    r1[l] = e; __syncthreads();
    for (int off = 128; off > 0; off >>= 1) {
        if (l < off) r1[l] += r1[l + off];
        __syncthreads();
    }
    double denom = r1[0];
    sw[l] = e / denom; __syncthreads();
    const size_t vbase = (size_t)s * LSEG * DD;
    for (int d = l; d < DD; d += 256) {
        double a2 = 0.0;
        for (int ll = 0; ll < LSEG; ll++) a2 += sw[ll] * vmat[vbase + (size_t)ll * DD + d];
        mem[(size_t)s * DD + d] = a2;
    }
}

// attention 2 + output gate (one batch): one block per token
__global__ __launch_bounds__(256) void attn2_kernel(const double* __restrict__ rq,
                                                    const double* __restrict__ rk,
                                                    const double* __restrict__ rv,
                                                    const double* __restrict__ xr,
                                                    const float* __restrict__ wg,
                                                    double* __restrict__ out2)
{
    const int t = blockIdx.x;
    const int sigma = t >> 8;          // t / LSEG
    const int tid = threadIdx.x;
    __shared__ double sqk[16];
    __shared__ double red[256];
    __shared__ double sw[16];
    __shared__ double sgate;

    const double* rqn = rq + (size_t)t * DD;
    {
        int s = tid >> 4, j = tid & 15;
        const double* rks = rk + (size_t)s * DD;
        double part = 0.0;
        for (int d = j; d < DD; d += 16) part += rqn[d] * rks[d];
#pragma unroll
        for (int off = 8; off > 0; off >>= 1) part += __shfl_down(part, off, 16);
        if (j == 0) sqk[s] = part;
    }
    double gp = 0.0;
    const double* xrn = xr + (size_t)t * HID;
    for (int hh = tid; hh < HID; hh += 256) gp += xrn[hh] * (double)wg[hh];
    red[tid] = gp; __syncthreads();
    for (int off = 128; off > 0; off >>= 1) {
        if (tid < off) red[tid] += red[tid + off];
        __syncthreads();
    }
    if (tid == 0) {
        const double inv = 1.0 / sqrt((double)DD);
        double m = -1e300;
        for (int ss = sigma; ss < 16; ss++) {
            double v = sqk[ss] * inv;
            sqk[ss] = v;
            if (v > m) m = v;
        }
        double sum = 0.0;
        for (int ss = sigma; ss < 16; ss++) {
            double e = exp(sqk[ss] - m);
            sw[ss] = e;
            sum += e;
        }
        double isum = 1.0 / sum;
        for (int ss = 0; ss < sigma; ss++) sw[ss] = 0.0;
        for (int ss = sigma; ss < 16; ss++) sw[ss] *= isum;
        sgate = 1.0 / (1.0 + exp(-red[0]));
    }
    __syncthreads();
    const double gte = sgate;
    for (int hh = tid; hh < HID; hh += 256) {
        double acc = 0.0;
        for (int ss = sigma; ss < 16; ss++) acc += sw[ss] * rv[(size_t)ss * HID + hh];
        out2[(size_t)t * HID + hh] = gte * acc;
    }
}

extern "C" void kernel_launch(void* const* d_in, const int* in_sizes, int n_in,
                              void* d_out, int out_size, void* d_ws, size_t ws_size,
                              hipStream_t stream)
{
    const float* x            = (const float*)d_in[0];
    const float* input_w      = (const float*)d_in[1];
    const float* conv_w       = (const float*)d_in[2];
    const float* conv_b       = (const float*)d_in[3];
    const float* gates_w      = (const float*)d_in[4];
    const float* gates_b      = (const float*)d_in[5];
    const float* forget_base  = (const float*)d_in[6];
    const float* output_w     = (const float*)d_in[7];
    const float* memory_slots = (const float*)d_in[8];
    const float* wq_w         = (const float*)d_in[9];
    const float* wk_w         = (const float*)d_in[10];
    const float* wv_w         = (const float*)d_in[11];
    const float* wg_w         = (const float*)d_in[12];
    const float* rq_w         = (const float*)d_in[13];
    const float* rk_w         = (const float*)d_in[14];
    const float* rv_w         = (const float*)d_in[15];
    float* out = (float*)d_out;

    // workspace: 3 big T*HID fp64 slots (50.3 MB each) + smalls ~= 154 MB total
    double* slotA = (double*)d_ws;
    double* slotB = slotA + TH;
    double* slotC = slotB + TH;
    double* spb    = slotC + TH;
    double* qbuf   = spb + HID;                       // 16*384
    double* membuf = qbuf + (size_t)SSEG * DD;        // 16*384
    double* rkbuf  = membuf + (size_t)SSEG * DD;      // 16*384
    double* rvbuf  = rkbuf + (size_t)SSEG * DD;       // 16*1536
    double* cA     = rvbuf + (size_t)SSEG * HID;      // 64*1536
    double* cB     = cA + (size_t)NCH * HID;
    double* cH0    = cB + (size_t)NCH * HID;

    dim3 blk(256);
    const int ewBlocks = (int)(TH / 256);             // 24576

    // once: softplus(forget_base); q = memory_slots @ wq_w.T
    spb_kernel<<<(HID + 255) / 256, blk, 0, stream>>>(forget_base, spb);
    gemm_tn<float, double, 0><<<dim3(1, DD / 64), blk, 0, stream>>>(
        memory_slots, wq_w, qbuf, (double*)nullptr, (const double*)nullptr, SSEG, DD, DD);

    for (int b = 0; b < BB; b++) {
        const float* xb   = x   + (size_t)b * TT * DIMW;
        float*       outb = out + (size_t)b * TT * DIMW;

        // xh0 = xb @ input_w[HID:,:].T  -> slotB
        gemm_tn<float, double, 0><<<dim3(TT / 64, HID / 64), blk, 0, stream>>>(
            xb, input_w + (size_t)HID * DIMW, slotB, (double*)nullptr,
            (const double*)nullptr, TT, HID, DIMW);
        // xh1 = causal conv(xh0) -> slotC
        conv_kernel<<<ewBlocks, blk, 0, stream>>>(slotB, conv_w, conv_b, slotC);
        // g = xh1 @ gates_w.T -> forget(slotA), inp(slotB)  (bias later)
        gemm_tn<double, double, 1><<<dim3(TT / 64, HID2 / 64), blk, 0, stream>>>(
            slotC, gates_w, slotA, slotB, (const double*)nullptr, TT, HID2, HID);
        // alpha(slotA), xh2(slotB) in-place, reads xh1(slotC)
        alpha_xh2_kernel<<<ewBlocks, blk, 0, stream>>>(slotA, slotB, slotC, spb, gates_b);
        // scan -> h(slotC)
        scan1_kernel<<<(NCH * HID) / 256, blk, 0, stream>>>(slotA, slotB, cA, cB);
        scan2_kernel<<<(HID + 255) / 256, blk, 0, stream>>>(cA, cB, cH0);
        scan3_kernel<<<(NCH * HID) / 256, blk, 0, stream>>>(slotA, slotB, cH0, slotC);
        // xh3 = silu(xb @ input_w[:HID].T) * xh2(slotB) -> slotA
        gemm_tn<float, double, 2><<<dim3(TT / 64, HID / 64), blk, 0, stream>>>(
            xb, input_w, slotA, (double*)nullptr, slotB, TT, HID, DIMW);
        // k/v projections -> slotB (xh2 dead)
        double* kmat = slotB;
        double* vmat = slotB + (size_t)TT * DD;
        gemm_tn<double, double, 0><<<dim3(TT / 64, DD / 64), blk, 0, stream>>>(
            slotA, wk_w, kmat, (double*)nullptr, (const double*)nullptr, TT, DD, HID);
        gemm_tn<double, double, 0><<<dim3(TT / 64, DD / 64), blk, 0, stream>>>(
            slotA, wv_w, vmat, (double*)nullptr, (const double*)nullptr, TT, DD, HID);
        // segment attention -> membuf
        attn1_kernel<<<SSEG, blk, 0, stream>>>(kmat, vmat, qbuf, membuf);
        // xr = gelu(xh3)*h -> slotA in-place (reads slotC)
        gelu_mul_kernel<<<ewBlocks, blk, 0, stream>>>(slotA, slotC);
        // rq = xr @ rq_w.T -> slotB (kv dead)
        gemm_tn<double, double, 0><<<dim3(TT / 64, DD / 64), blk, 0, stream>>>(
            slotA, rq_w, slotB, (double*)nullptr, (const double*)nullptr, TT, DD, HID);
        // rk = mem @ rk_w.T ; rv = mem @ rv_w.T
        gemm_tn<double, double, 0><<<dim3(1, DD / 64), blk, 0, stream>>>(
            membuf, rk_w, rkbuf, (double*)nullptr, (const double*)nullptr, SSEG, DD, DD);
        gemm_tn<double, double, 0><<<dim3(1, HID / 64), blk, 0, stream>>>(
            membuf, rv_w, rvbuf, (double*)nullptr, (const double*)nullptr, SSEG, HID, DD);
        // cross attention + gate -> out2(slotC) (h dead)
        attn2_kernel<<<TT, blk, 0, stream>>>(slotB, rkbuf, rvbuf, slotA, wg_w, slotC);
        // final projection -> d_out (fp32)
        gemm_tn<double, float, 0><<<dim3(TT / 64, DIMW / 64), blk, 0, stream>>>(
            slotC, output_w, outb, (float*)nullptr, (const double*)nullptr, TT, DIMW, HID);
    }
}